// Round 4
// baseline (4462.960 us; speedup 1.0000x reference)
//
#include <hip/hip_runtime.h>
#include <hip/hip_bf16.h>
#include <math.h>

#define D_MODEL 1024
#define D_INNER 2048
#define D_STATE 16
#define DT_RANK 64
#define BB 4
#define LL 4096
#define NROWS (BB * LL)   // 16384

typedef __hip_bfloat16 bf16;

__device__ __forceinline__ float silu_f(float x) { return x / (1.f + __expf(-x)); }
__device__ __forceinline__ float softplus_f(float x) { return x > 20.f ? x : log1pf(__expf(x)); }
__device__ __forceinline__ float bf2f(bf16 v) { return __bfloat162float(v); }
__device__ __forceinline__ bf16 f2bf(float v) { return __float2bfloat16(v); }

// decode 8 consecutive bf16 (16-byte aligned) to fp32
__device__ __forceinline__ void load8_bf16(const bf16* p, float* f) {
    uint4 raw = *(const uint4*)p;
    unsigned int w0 = raw.x, w1 = raw.y, w2 = raw.z, w3 = raw.w;
    f[0] = __uint_as_float((w0 & 0xffffu) << 16);
    f[1] = __uint_as_float(w0 & 0xffff0000u);
    f[2] = __uint_as_float((w1 & 0xffffu) << 16);
    f[3] = __uint_as_float(w1 & 0xffff0000u);
    f[4] = __uint_as_float((w2 & 0xffffu) << 16);
    f[5] = __uint_as_float(w2 & 0xffff0000u);
    f[6] = __uint_as_float((w3 & 0xffffu) << 16);
    f[7] = __uint_as_float(w3 & 0xffff0000u);
}

// ---------------------------------------------------------------------------
// Input dtype detection: decode the first 2048 uint16s of x as bf16. Genuine
// bf16 N(0,1) data stays small & finite. fp32 N(0,1) data read this way has
// uniform-random exponent bytes in the even elements -> NaN / huge values.
// flag: 1 = inputs are fp32, 0 = inputs are bf16.
// ---------------------------------------------------------------------------
__global__ void detect_dtype(const void* xsrc, int* flag) {
    const unsigned short* p = (const unsigned short*)xsrc;
    int tid = threadIdx.x;
    int bad = 0;
    for (int i = tid; i < 2048; i += 256) {
        float v = __uint_as_float(((unsigned int)p[i]) << 16);
        if (!isfinite(v) || fabsf(v) > 1e6f) bad = 1;
    }
    __shared__ int sbad;
    if (tid == 0) sbad = 0;
    __syncthreads();
    if (bad) atomicOr(&sbad, 1);
    __syncthreads();
    if (tid == 0) *flag = sbad;
}

// Canonicalize an input tensor to bf16 (copy if already bf16, downcast if fp32)
__global__ __launch_bounds__(256) void convert_to_bf16(
    const void* __restrict__ src, bf16* __restrict__ dst, int n,
    const int* __restrict__ flag)
{
    int i = blockIdx.x * 256 + threadIdx.x;
    if (i >= n) return;
    if (*flag)
        dst[i] = f2bf(((const float*)src)[i]);
    else
        dst[i] = ((const bf16*)src)[i];
}

// ---------------------------------------------------------------------------
// bf16-in / bf16-out GEMM, fp32 accumulate: C[M,N] = A[M,K] @ B[N,K]^T
// B row-major (N,K). Tile 128(M) x 64(N) x 16(K), 256 threads, 8x4 microtile.
// EPI: 0 = none, 1 = softplus(x + bias[n]).
// ---------------------------------------------------------------------------
template <int EPI>
__global__ __launch_bounds__(256) void gemm_tn(
    const bf16* __restrict__ A, int lda,
    const bf16* __restrict__ Bw, int K,
    const bf16* __restrict__ bias,
    bf16* __restrict__ C, int ldc,
    int M, int N)
{
    __shared__ float As[16][132];
    __shared__ float Bs[16][68];

    const int tid = threadIdx.x;
    const int m0 = blockIdx.y * 128;
    const int n0 = blockIdx.x * 64;
    const int tx = tid & 15;
    const int ty = tid >> 4;

    float acc[8][4];
#pragma unroll
    for (int i = 0; i < 8; i++)
#pragma unroll
        for (int j = 0; j < 4; j++) acc[i][j] = 0.f;

    for (int k0 = 0; k0 < K; k0 += 16) {
        {
            int row = tid >> 1;
            int kc = (tid & 1) * 8;
            float f[8];
            load8_bf16(A + (size_t)(m0 + row) * lda + k0 + kc, f);
#pragma unroll
            for (int j = 0; j < 8; j++) As[kc + j][row] = f[j];
        }
        if (tid < 128) {
            int row = tid >> 1;
            int kc = (tid & 1) * 8;
            float f[8] = {0.f, 0.f, 0.f, 0.f, 0.f, 0.f, 0.f, 0.f};
            if (n0 + row < N)
                load8_bf16(Bw + (size_t)(n0 + row) * K + k0 + kc, f);
#pragma unroll
            for (int j = 0; j < 8; j++) Bs[kc + j][row] = f[j];
        }
        __syncthreads();

#pragma unroll
        for (int k = 0; k < 16; k++) {
            float4 a0 = *(const float4*)&As[k][ty * 8];
            float4 a1 = *(const float4*)&As[k][ty * 8 + 4];
            float4 bq = *(const float4*)&Bs[k][tx * 4];
            float a[8] = {a0.x, a0.y, a0.z, a0.w, a1.x, a1.y, a1.z, a1.w};
            float b[4] = {bq.x, bq.y, bq.z, bq.w};
#pragma unroll
            for (int i = 0; i < 8; i++)
#pragma unroll
                for (int j = 0; j < 4; j++)
                    acc[i][j] = fmaf(a[i], b[j], acc[i][j]);
        }
        __syncthreads();
    }

#pragma unroll
    for (int i = 0; i < 8; i++) {
        int m = m0 + ty * 8 + i;
#pragma unroll
        for (int j = 0; j < 4; j++) {
            int n = n0 + tx * 4 + j;
            if (n >= N) continue;
            float v = acc[i][j];
            if (EPI == 1) v = softplus_f(v + bf2f(bias[n]));
            C[(size_t)m * ldc + n] = f2bf(v);
        }
    }
}

// ---------------------------------------------------------------------------
// Causal depthwise conv1d (width 4) + bias + SiLU. bf16 in/out, fp32 math.
// ---------------------------------------------------------------------------
__global__ __launch_bounds__(256) void conv_silu(
    const bf16* __restrict__ u,
    bf16* __restrict__ u_c,
    const bf16* __restrict__ w,
    const bf16* __restrict__ bias)
{
    int gid = blockIdx.x * 256 + threadIdx.x;
    if (gid >= NROWS * D_INNER) return;
    int d = gid & (D_INNER - 1);
    int row = gid >> 11;
    int l = row & (LL - 1);
    float acc = bf2f(bias[d]);
#pragma unroll
    for (int t = 0; t < 4; t++) {
        int ls = l - 3 + t;
        if (ls >= 0)
            acc = fmaf(bf2f(w[d * 4 + t]), bf2f(u[(size_t)(row - 3 + t) * D_INNER + d]), acc);
    }
    u_c[(size_t)row * D_INNER + d] = f2bf(silu_f(acc));
}

// ---------------------------------------------------------------------------
// Selective scan. 16 lanes per (b,d) channel, one state n per lane.
// Fuses y = scan + u_c*D, then y * silu(z). Writes in-place over u_c
// (ucin/yg alias: no __restrict__ on them).
// ---------------------------------------------------------------------------
__global__ __launch_bounds__(256) void scan_kernel(
    const bf16* __restrict__ delta,   // (NROWS, D_INNER)
    const bf16* ucin,                 // (NROWS, D_INNER)  [aliases yg]
    const bf16* __restrict__ x_dbl,   // (NROWS, 96)
    const bf16* __restrict__ z,       // (NROWS, D_INNER)
    const bf16* __restrict__ A_log,   // (D_INNER, 16)
    const bf16* __restrict__ Dvec,    // (D_INNER)
    bf16* yg)
{
    const int tid = threadIdx.x;
    const int n = tid & 15;
    const int ch = tid >> 4;
    const int b = blockIdx.x >> 7;
    const int d = ((blockIdx.x & 127) << 4) + ch;

    const float Acoef = -__expf(bf2f(A_log[d * D_STATE + n]));
    const float Dv = bf2f(Dvec[d]);
    float h = 0.f;

    size_t idxD = (size_t)b * LL * D_INNER + d;
    size_t idxB = (size_t)b * LL * 96 + DT_RANK + n;
    size_t idxW = idxD;

    float dl = bf2f(delta[idxD]);
    float uv = bf2f(ucin[idxD]);
    float Bv = bf2f(x_dbl[idxB]);
    float Cv = bf2f(x_dbl[idxB + D_STATE]);
    float zv = bf2f(z[idxD]);

    for (int l = 0; l < LL; l++) {
        float dl_n = 0.f, uv_n = 0.f, Bv_n = 0.f, Cv_n = 0.f, zv_n = 0.f;
        if (l + 1 < LL) {
            idxD += D_INNER; idxB += 96;
            dl_n = bf2f(delta[idxD]);
            uv_n = bf2f(ucin[idxD]);
            Bv_n = bf2f(x_dbl[idxB]);
            Cv_n = bf2f(x_dbl[idxB + D_STATE]);
            zv_n = bf2f(z[idxD]);
        }
        float dA = __expf(dl * Acoef);
        h = fmaf(dA, h, dl * uv * Bv);
        float p = h * Cv;
        p += __shfl_xor(p, 1, 64);
        p += __shfl_xor(p, 2, 64);
        p += __shfl_xor(p, 4, 64);
        p += __shfl_xor(p, 8, 64);
        if (n == 0) {
            float y = p + uv * Dv;
            yg[idxW] = f2bf(y * silu_f(zv));
        }
        idxW += D_INNER;
        dl = dl_n; uv = uv_n; Bv = Bv_n; Cv = Cv_n; zv = zv_n;
    }
}

// ---------------------------------------------------------------------------
// LayerNorm over last dim (1024). bf16 input; output dtype per flag
// (1 = fp32, 0 = bf16). Block (256) per row, 4 elems/thread.
// ---------------------------------------------------------------------------
__global__ __launch_bounds__(256) void out_ln(
    const bf16* __restrict__ o,
    const bf16* __restrict__ lw,
    const bf16* __restrict__ lb,
    void* __restrict__ outv,
    const int* __restrict__ flag)
{
    __shared__ float sm[4];
    const int row = blockIdx.x;
    const int tid = threadIdx.x;
    const int lane = tid & 63;
    const int wid = tid >> 6;
    const int c = tid * 4;

    const bf16* rp = o + (size_t)row * 1024 + c;
    float v0 = bf2f(rp[0]), v1 = bf2f(rp[1]), v2 = bf2f(rp[2]), v3 = bf2f(rp[3]);

    float s = v0 + v1 + v2 + v3;
#pragma unroll
    for (int off = 1; off < 64; off <<= 1) s += __shfl_xor(s, off, 64);
    if (lane == 0) sm[wid] = s;
    __syncthreads();
    float mu = (sm[0] + sm[1] + sm[2] + sm[3]) * (1.f / 1024.f);
    __syncthreads();

    float dx0 = v0 - mu, dx1 = v1 - mu, dx2 = v2 - mu, dx3 = v3 - mu;
    float q = dx0 * dx0 + dx1 * dx1 + dx2 * dx2 + dx3 * dx3;
#pragma unroll
    for (int off = 1; off < 64; off <<= 1) q += __shfl_xor(q, off, 64);
    if (lane == 0) sm[wid] = q;
    __syncthreads();
    float var = (sm[0] + sm[1] + sm[2] + sm[3]) * (1.f / 1024.f);
    float inv = rsqrtf(var + 1e-5f);

    float w0 = bf2f(lw[c]), w1 = bf2f(lw[c + 1]), w2 = bf2f(lw[c + 2]), w3 = bf2f(lw[c + 3]);
    float b0 = bf2f(lb[c]), b1 = bf2f(lb[c + 1]), b2 = bf2f(lb[c + 2]), b3 = bf2f(lb[c + 3]);
    float r0 = dx0 * inv * w0 + b0;
    float r1 = dx1 * inv * w1 + b1;
    float r2 = dx2 * inv * w2 + b2;
    float r3 = dx3 * inv * w3 + b3;

    if (*flag) {
        float4* wp = (float4*)((float*)outv + (size_t)row * 1024 + c);
        *wp = make_float4(r0, r1, r2, r3);
    } else {
        bf16* wp = (bf16*)outv + (size_t)row * 1024 + c;
        wp[0] = f2bf(r0); wp[1] = f2bf(r1); wp[2] = f2bf(r2); wp[3] = f2bf(r3);
    }
}

// ---------------------------------------------------------------------------
extern "C" void kernel_launch(void* const* d_in, const int* in_sizes, int n_in,
                              void* d_out, int out_size, void* d_ws, size_t ws_size,
                              hipStream_t stream)
{
    const void* x          = d_in[0];
    const void* in_proj_w  = d_in[1];
    const void* conv_w     = d_in[2];
    const void* conv_b     = d_in[3];
    const void* x_proj_w   = d_in[4];
    const void* dt_proj_w  = d_in[5];
    const void* dt_proj_b  = d_in[6];
    const void* A_log      = d_in[7];
    const void* Dvec       = d_in[8];
    const void* out_proj_w = d_in[9];
    const void* ln_w       = d_in[10];
    const void* ln_b       = d_in[11];

    // ---- workspace layout (bf16 elements) -------------------------------
    // bufA [0,nBig)        : u -> x_proj_w copy -> delta -> out_proj_w copy
    // bufZ [nBig,2n)       : z -> y_out (stage 6 result)
    // bufC [2n,3n)         : x copy + in_proj_w copy -> u_c / y_gated
    // bufX [3n, 3n+1.57M)  : x_dbl
    // bufS [.., +196608)   : flag + small-const bf16 copies
    size_t nBig = (size_t)NROWS * D_INNER;           // 33,554,432
    size_t xdblN = (size_t)NROWS * 96;               // 1,572,864
    size_t need = (3 * nBig + xdblN + 196608) * 2;   // ~195.5 MB
    if (ws_size < need) {
        hipMemsetAsync(d_out, 0, (size_t)out_size * 2, stream);
        return;
    }

    bf16* bufA = (bf16*)d_ws;
    bf16* bufZ = bufA + nBig;
    bf16* bufC = bufZ + nBig;
    bf16* bufX = bufC + nBig;       // x_dbl
    bf16* bufS = bufX + xdblN;      // small consts

    // small-const slab layout
    int*  flag   = (int*)bufS;                 // 16 bf16 = 32B reserved
    bf16* c_convw = bufS + 16;                 // 8192
    bf16* c_convb = c_convw + 8192;            // 2048
    bf16* c_dtw   = c_convb + 2048;            // 131072
    bf16* c_dtb   = c_dtw + 131072;            // 2048
    bf16* c_Alog  = c_dtb + 2048;              // 32768
    bf16* c_D     = c_Alog + 32768;            // 2048
    bf16* c_lnw   = c_D + 2048;                // 1024
    bf16* c_lnb   = c_lnw + 1024;              // 1024

    // big-buffer phase overlays
    bf16* c_x    = bufC;                       // 16,777,216 (dies at stage 2)
    bf16* c_wip  = bufC + (size_t)NROWS * 1024;// 4,194,304  (dies at stage 2)
    bf16* c_xpw  = bufA;                       // 196,608 (between u and delta)
    bf16* c_opw  = bufA;                       // 2,097,152 (after delta dies)
    bf16* u      = bufA;
    bf16* delta  = bufA;
    bf16* zbuf   = bufZ;
    bf16* y_out  = bufZ;
    bf16* u_c    = bufC;
    bf16* x_dbl  = bufX;

    dim3 blk(256);
    auto cvt = [&](const void* src, bf16* dst, int n) {
        convert_to_bf16<<<dim3((n + 255) / 256), blk, 0, stream>>>(src, dst, n, flag);
    };

    // 0. detect input dtype
    detect_dtype<<<dim3(1), blk, 0, stream>>>(x, flag);

    // small consts (slab untouched by all stages)
    cvt(conv_w, c_convw, D_INNER * 4);
    cvt(conv_b, c_convb, D_INNER);
    cvt(dt_proj_w, c_dtw, D_INNER * DT_RANK);
    cvt(dt_proj_b, c_dtb, D_INNER);
    cvt(A_log, c_Alog, D_INNER * D_STATE);
    cvt(Dvec, c_D, D_INNER);
    cvt(ln_w, c_lnw, D_MODEL);
    cvt(ln_b, c_lnb, D_MODEL);

    // x + in_proj_w canonical copies (live in bufC until stage 2)
    cvt(x, c_x, NROWS * D_MODEL);
    cvt(in_proj_w, c_wip, 2 * D_INNER * D_MODEL);

    // 1a. u = x @ in_proj_w[0:2048]^T
    gemm_tn<0><<<dim3(D_INNER / 64, NROWS / 128), blk, 0, stream>>>(
        c_x, D_MODEL, c_wip, D_MODEL, nullptr, u, D_INNER, NROWS, D_INNER);
    // 1b. z = x @ in_proj_w[2048:4096]^T
    gemm_tn<0><<<dim3(D_INNER / 64, NROWS / 128), blk, 0, stream>>>(
        c_x, D_MODEL, c_wip + (size_t)D_INNER * D_MODEL, D_MODEL, nullptr,
        zbuf, D_INNER, NROWS, D_INNER);

    // 2. conv + SiLU -> u_c (overwrites c_x/c_wip; both dead)
    conv_silu<<<dim3((NROWS * D_INNER) / 256), blk, 0, stream>>>(u, u_c, c_convw, c_convb);

    // 3. x_proj (copy into bufA first; u is dead)
    cvt(x_proj_w, c_xpw, 96 * D_INNER);
    gemm_tn<0><<<dim3(2, NROWS / 128), blk, 0, stream>>>(
        u_c, D_INNER, c_xpw, D_INNER, nullptr, x_dbl, 96, NROWS, 96);

    // 4. dt_proj + softplus -> delta (overwrites c_xpw; dead)
    gemm_tn<1><<<dim3(D_INNER / 64, NROWS / 128), blk, 0, stream>>>(
        x_dbl, 96, c_dtw, DT_RANK, c_dtb, delta, D_INNER, NROWS, D_INNER);

    // 5. selective scan + D-skip + gate (in-place into u_c)
    scan_kernel<<<dim3(512), blk, 0, stream>>>(delta, u_c, x_dbl, zbuf, c_Alog, c_D, u_c);

    // 6. out_proj -> y_out in bufZ (z dead; delta dead so bufA takes the copy)
    cvt(out_proj_w, c_opw, D_MODEL * D_INNER);
    gemm_tn<0><<<dim3(D_MODEL / 64, NROWS / 128), blk, 0, stream>>>(
        u_c, D_INNER, c_opw, D_INNER, nullptr, y_out, D_MODEL, NROWS, D_MODEL);

    // 7. LayerNorm -> d_out (dtype per flag)
    out_ln<<<dim3(NROWS), blk, 0, stream>>>(y_out, c_lnw, c_lnb, d_out, flag);
}

// Round 6
// 1095.371 us; speedup vs baseline: 4.0744x; 4.0744x over previous
//
#include <hip/hip_runtime.h>
#include <hip/hip_bf16.h>
#include <math.h>

#define D_MODEL 1024
#define D_INNER 2048
#define D_STATE 16
#define DT_RANK 64
#define BB 4
#define LL 4096
#define NROWS (BB * LL)   // 16384
#define NCHUNK 16
#define TCHUNK 256        // NCHUNK * TCHUNK == LL

typedef __hip_bfloat16 bf16;
typedef __attribute__((ext_vector_type(8))) short short8;   // MFMA A/B frag (8 bf16)
typedef __attribute__((ext_vector_type(4))) float floatx4;  // MFMA C/D frag

__device__ __forceinline__ float silu_f(float x) { return x / (1.f + __expf(-x)); }
__device__ __forceinline__ float softplus_f(float x) { return x > 20.f ? x : log1pf(__expf(x)); }
__device__ __forceinline__ float bf2f(bf16 v) { return __bfloat162float(v); }
__device__ __forceinline__ bf16 f2bf(float v) { return __float2bfloat16(v); }

// decode 8 consecutive bf16 (16-byte aligned) to fp32
__device__ __forceinline__ void load8_bf16(const bf16* p, float* f) {
    uint4 raw = *(const uint4*)p;
    unsigned int w0 = raw.x, w1 = raw.y, w2 = raw.z, w3 = raw.w;
    f[0] = __uint_as_float((w0 & 0xffffu) << 16);
    f[1] = __uint_as_float(w0 & 0xffff0000u);
    f[2] = __uint_as_float((w1 & 0xffffu) << 16);
    f[3] = __uint_as_float(w1 & 0xffff0000u);
    f[4] = __uint_as_float((w2 & 0xffffu) << 16);
    f[5] = __uint_as_float(w2 & 0xffff0000u);
    f[6] = __uint_as_float((w3 & 0xffffu) << 16);
    f[7] = __uint_as_float(w3 & 0xffff0000u);
}

// ---------------------------------------------------------------------------
// Input dtype detection (1 = fp32 inputs, 0 = bf16 inputs).
// ---------------------------------------------------------------------------
__global__ void detect_dtype(const void* xsrc, int* flag) {
    const unsigned short* p = (const unsigned short*)xsrc;
    int tid = threadIdx.x;
    int bad = 0;
    for (int i = tid; i < 2048; i += 256) {
        float v = __uint_as_float(((unsigned int)p[i]) << 16);
        if (!isfinite(v) || fabsf(v) > 1e6f) bad = 1;
    }
    __shared__ int sbad;
    if (tid == 0) sbad = 0;
    __syncthreads();
    if (bad) atomicOr(&sbad, 1);
    __syncthreads();
    if (tid == 0) *flag = sbad;
}

__global__ __launch_bounds__(256) void convert_to_bf16(
    const void* __restrict__ src, bf16* __restrict__ dst, int n,
    const int* __restrict__ flag)
{
    int i = blockIdx.x * 256 + threadIdx.x;
    if (i >= n) return;
    if (*flag)
        dst[i] = f2bf(((const float*)src)[i]);
    else
        dst[i] = ((const bf16*)src)[i];
}

// ---------------------------------------------------------------------------
// MFMA bf16 GEMM: C[M,N] = A[M,K] @ W[N,K]^T, fp32 accumulate.
// 128x128 tile, BK=32, 256 threads = 4 waves in 2x2; each wave 64x64 via
// 4x4 grid of 16x16x32 MFMAs. A/B frag: lane holds row (lane&15), k-slice
// (lane>>4)*8..+7. C/D frag: col=lane&15, row=(lane>>4)*4+reg [m89/m91].
// Staging: 512 chunks of 8 bf16 (16B) per tile; 2 chunks/thread.
// EPI: 0 none, 1 softplus(x + bias[n]). M%128==0, K%32==0; N bounds-checked.
// ---------------------------------------------------------------------------
template <int EPI>
__global__ __launch_bounds__(256) void gemm_mfma(
    const bf16* __restrict__ A, int lda,
    const bf16* __restrict__ W, int ldw, int K,
    const bf16* __restrict__ bias,
    bf16* __restrict__ C, int ldc,
    int M, int N)
{
    __shared__ short As[128 * 32];   // [m][k] rows of 32 bf16
    __shared__ short Bs[128 * 32];   // [n][k]

    const int tid = threadIdx.x;
    const int m0 = blockIdx.y * 128;
    const int n0 = blockIdx.x * 128;
    const int wid = tid >> 6;
    const int lane = tid & 63;
    const int wm = wid & 1;          // wave row (2 waves over M)
    const int wn = wid >> 1;         // wave col (2 waves over N)
    const int lm = lane & 15;
    const int quad = lane >> 4;

    floatx4 acc[4][4];
#pragma unroll
    for (int i = 0; i < 4; i++)
#pragma unroll
        for (int j = 0; j < 4; j++) acc[i][j] = (floatx4){0.f, 0.f, 0.f, 0.f};

    for (int k0 = 0; k0 < K; k0 += 32) {
        // stage A tile: 128 rows x 32 bf16 = 512 x (8 bf16 / 16B chunks)
#pragma unroll
        for (int s = 0; s < 2; s++) {
            int f = tid * 2 + s;         // chunk id 0..511
            int row = f >> 2;            // 0..127
            int seg = f & 3;             // 8-elem segment 0..3
            uint4 v = *(const uint4*)(A + (size_t)(m0 + row) * lda + k0 + seg * 8);
            *(uint4*)&As[row * 32 + seg * 8] = v;
        }
        // stage W tile (zero-pad rows beyond N)
#pragma unroll
        for (int s = 0; s < 2; s++) {
            int f = tid * 2 + s;
            int row = f >> 2;
            int seg = f & 3;
            uint4 v = make_uint4(0u, 0u, 0u, 0u);
            if (n0 + row < N)
                v = *(const uint4*)(W + (size_t)(n0 + row) * ldw + k0 + seg * 8);
            *(uint4*)&Bs[row * 32 + seg * 8] = v;
        }
        __syncthreads();

        short8 af[4], bfr[4];
#pragma unroll
        for (int mt = 0; mt < 4; mt++)
            af[mt] = *(const short8*)&As[(wm * 64 + mt * 16 + lm) * 32 + quad * 8];
#pragma unroll
        for (int nt = 0; nt < 4; nt++)
            bfr[nt] = *(const short8*)&Bs[(wn * 64 + nt * 16 + lm) * 32 + quad * 8];

#pragma unroll
        for (int mt = 0; mt < 4; mt++)
#pragma unroll
            for (int nt = 0; nt < 4; nt++)
                acc[mt][nt] = __builtin_amdgcn_mfma_f32_16x16x32_bf16(
                    af[mt], bfr[nt], acc[mt][nt], 0, 0, 0);
        __syncthreads();
    }

    // epilogue: col = lane&15, row = quad*4 + r
#pragma unroll
    for (int mt = 0; mt < 4; mt++) {
#pragma unroll
        for (int nt = 0; nt < 4; nt++) {
            int col = n0 + wn * 64 + nt * 16 + lm;
            if (col >= N) continue;
            int rbase = m0 + wm * 64 + mt * 16 + quad * 4;
#pragma unroll
            for (int r = 0; r < 4; r++) {
                float v = acc[mt][nt][r];
                if (EPI == 1) v = softplus_f(v + bf2f(bias[col]));
                C[(size_t)(rbase + r) * ldc + col] = f2bf(v);
            }
        }
    }
}

// ---------------------------------------------------------------------------
// Causal depthwise conv1d (width 4) + bias + SiLU. bf16 in/out, fp32 math.
// ---------------------------------------------------------------------------
__global__ __launch_bounds__(256) void conv_silu(
    const bf16* __restrict__ u,
    bf16* __restrict__ u_c,
    const bf16* __restrict__ w,
    const bf16* __restrict__ bias)
{
    int gid = blockIdx.x * 256 + threadIdx.x;
    if (gid >= NROWS * D_INNER) return;
    int d = gid & (D_INNER - 1);
    int row = gid >> 11;
    int l = row & (LL - 1);
    float acc = bf2f(bias[d]);
#pragma unroll
    for (int t = 0; t < 4; t++) {
        int ls = l - 3 + t;
        if (ls >= 0)
            acc = fmaf(bf2f(w[d * 4 + t]), bf2f(u[(size_t)(row - 3 + t) * D_INNER + d]), acc);
    }
    u_c[(size_t)row * D_INNER + d] = f2bf(silu_f(acc));
}

// ---------------------------------------------------------------------------
// Chunked selective scan. h_t = dA_t h + dBu_t is linear -> per-chunk
// (P = prod dA, S = local end state) combine associatively.
// Phase 1: per-chunk P,S with h_init=0. Thread owns (b,d): h[16],P[16] regs.
// idx layout for P/S: ((b*16 + c)*16 + n)*2048 + d
// ---------------------------------------------------------------------------
__global__ __launch_bounds__(256) void scan_p1(
    const bf16* __restrict__ delta,   // (NROWS, 2048)
    const bf16* __restrict__ uc,      // (NROWS, 2048)
    const bf16* __restrict__ x_dbl,   // (NROWS, 96): B at col 64
    const bf16* __restrict__ A_log,   // (2048, 16)
    float* __restrict__ Pbuf, float* __restrict__ Sbuf)
{
    __shared__ float Bsh[TCHUNK * 16];
    const int tid = threadIdx.x;
    const int bx = blockIdx.x;
    const int b = bx >> 7;
    const int c = (bx >> 3) & 15;
    const int dt = bx & 7;
    const int d = dt * 256 + tid;
    const int rowb = b * LL + c * TCHUNK;

    {
        float f[16];
        const bf16* p = x_dbl + (size_t)(rowb + tid) * 96 + DT_RANK;
        load8_bf16(p, f);
        load8_bf16(p + 8, f + 8);
#pragma unroll
        for (int n = 0; n < 16; n++) Bsh[tid * 16 + n] = f[n];
    }

    float Ac[16];
    {
        float f[16];
        load8_bf16(A_log + (size_t)d * 16, f);
        load8_bf16(A_log + (size_t)d * 16 + 8, f + 8);
#pragma unroll
        for (int n = 0; n < 16; n++) Ac[n] = -__expf(f[n]);
    }
    __syncthreads();

    float h[16], Pp[16];
#pragma unroll
    for (int n = 0; n < 16; n++) { h[n] = 0.f; Pp[n] = 1.f; }

    size_t g = (size_t)rowb * 2048 + d;
    float dl = bf2f(delta[g]);
    float uv = bf2f(uc[g]);
    for (int t = 0; t < TCHUNK; t++) {
        float dl_n = 0.f, uv_n = 0.f;
        if (t + 1 < TCHUNK) {
            g += 2048;
            dl_n = bf2f(delta[g]);
            uv_n = bf2f(uc[g]);
        }
        float dlu = dl * uv;
#pragma unroll
        for (int n = 0; n < 16; n++) {
            float dA = __expf(dl * Ac[n]);
            h[n] = fmaf(dA, h[n], dlu * Bsh[t * 16 + n]);
            Pp[n] *= dA;
        }
        dl = dl_n; uv = uv_n;
    }

    size_t base = (((size_t)b * NCHUNK + c) * 16) * 2048 + d;
#pragma unroll
    for (int n = 0; n < 16; n++) {
        Pbuf[base + (size_t)n * 2048] = Pp[n];
        Sbuf[base + (size_t)n * 2048] = h[n];
    }
}

// Phase 2: inter-chunk scan (16 steps) per (b,n,d); h_init overwrites Pbuf.
__global__ __launch_bounds__(256) void scan_p2(
    float* __restrict__ Pbuf, const float* __restrict__ Sbuf)
{
    int gid = blockIdx.x * 256 + threadIdx.x;   // 131072 total
    int b = gid >> 15;
    int n = (gid >> 11) & 15;
    int d = gid & 2047;
    float hinit = 0.f;
    for (int c = 0; c < NCHUNK; c++) {
        size_t idx = (((size_t)b * NCHUNK + c) * 16 + n) * 2048 + d;
        float p = Pbuf[idx];
        float s = Sbuf[idx];
        Pbuf[idx] = hinit;
        hinit = fmaf(p, hinit, s);
    }
}

// Phase 3: recompute with true h_init; fuse y = sum h*C + u*D, gate silu(z).
__global__ __launch_bounds__(256) void scan_p3(
    const bf16* __restrict__ delta,
    const bf16* uc,                   // aliases output
    const bf16* __restrict__ x_dbl,   // B at 64, C at 80
    const bf16* __restrict__ z,
    const bf16* __restrict__ A_log,
    const bf16* __restrict__ Dvec,
    const float* __restrict__ Hinit,  // == Pbuf after phase 2
    bf16* yg)
{
    __shared__ float Bsh[TCHUNK * 16];
    __shared__ float Csh[TCHUNK * 16];
    const int tid = threadIdx.x;
    const int bx = blockIdx.x;
    const int b = bx >> 7;
    const int c = (bx >> 3) & 15;
    const int dt = bx & 7;
    const int d = dt * 256 + tid;
    const int rowb = b * LL + c * TCHUNK;

    {
        float f[16];
        const bf16* p = x_dbl + (size_t)(rowb + tid) * 96 + DT_RANK;
        load8_bf16(p, f);
        load8_bf16(p + 8, f + 8);
#pragma unroll
        for (int n = 0; n < 16; n++) Bsh[tid * 16 + n] = f[n];
        load8_bf16(p + 16, f);
        load8_bf16(p + 24, f + 8);
#pragma unroll
        for (int n = 0; n < 16; n++) Csh[tid * 16 + n] = f[n];
    }

    float Ac[16];
    {
        float f[16];
        load8_bf16(A_log + (size_t)d * 16, f);
        load8_bf16(A_log + (size_t)d * 16 + 8, f + 8);
#pragma unroll
        for (int n = 0; n < 16; n++) Ac[n] = -__expf(f[n]);
    }
    const float Dv = bf2f(Dvec[d]);
    __syncthreads();

    float h[16];
    size_t base = (((size_t)b * NCHUNK + c) * 16) * 2048 + d;
#pragma unroll
    for (int n = 0; n < 16; n++) h[n] = Hinit[base + (size_t)n * 2048];

    size_t g = (size_t)rowb * 2048 + d;
    float dl = bf2f(delta[g]);
    float uv = bf2f(uc[g]);
    float zv = bf2f(z[g]);
    size_t gw = g;
    for (int t = 0; t < TCHUNK; t++) {
        float dl_n = 0.f, uv_n = 0.f, zv_n = 0.f;
        if (t + 1 < TCHUNK) {
            g += 2048;
            dl_n = bf2f(delta[g]);
            uv_n = bf2f(uc[g]);
            zv_n = bf2f(z[g]);
        }
        float dlu = dl * uv;
        float y = 0.f;
#pragma unroll
        for (int n = 0; n < 16; n++) {
            float dA = __expf(dl * Ac[n]);
            h[n] = fmaf(dA, h[n], dlu * Bsh[t * 16 + n]);
            y = fmaf(h[n], Csh[t * 16 + n], y);
        }
        y = fmaf(uv, Dv, y);
        yg[gw] = f2bf(y * silu_f(zv));
        gw += 2048;
        dl = dl_n; uv = uv_n; zv = zv_n;
    }
}

// ---------------------------------------------------------------------------
// LayerNorm over last dim (1024). Output dtype per flag (1=fp32, 0=bf16).
// ---------------------------------------------------------------------------
__global__ __launch_bounds__(256) void out_ln(
    const bf16* __restrict__ o,
    const bf16* __restrict__ lw,
    const bf16* __restrict__ lb,
    void* __restrict__ outv,
    const int* __restrict__ flag)
{
    __shared__ float sm[4];
    const int row = blockIdx.x;
    const int tid = threadIdx.x;
    const int lane = tid & 63;
    const int wid = tid >> 6;
    const int c = tid * 4;

    const bf16* rp = o + (size_t)row * 1024 + c;
    float v0 = bf2f(rp[0]), v1 = bf2f(rp[1]), v2 = bf2f(rp[2]), v3 = bf2f(rp[3]);

    float s = v0 + v1 + v2 + v3;
#pragma unroll
    for (int off = 1; off < 64; off <<= 1) s += __shfl_xor(s, off, 64);
    if (lane == 0) sm[wid] = s;
    __syncthreads();
    float mu = (sm[0] + sm[1] + sm[2] + sm[3]) * (1.f / 1024.f);
    __syncthreads();

    float dx0 = v0 - mu, dx1 = v1 - mu, dx2 = v2 - mu, dx3 = v3 - mu;
    float q = dx0 * dx0 + dx1 * dx1 + dx2 * dx2 + dx3 * dx3;
#pragma unroll
    for (int off = 1; off < 64; off <<= 1) q += __shfl_xor(q, off, 64);
    if (lane == 0) sm[wid] = q;
    __syncthreads();
    float var = (sm[0] + sm[1] + sm[2] + sm[3]) * (1.f / 1024.f);
    float inv = rsqrtf(var + 1e-5f);

    float w0 = bf2f(lw[c]), w1 = bf2f(lw[c + 1]), w2 = bf2f(lw[c + 2]), w3 = bf2f(lw[c + 3]);
    float b0 = bf2f(lb[c]), b1 = bf2f(lb[c + 1]), b2 = bf2f(lb[c + 2]), b3 = bf2f(lb[c + 3]);
    float r0 = dx0 * inv * w0 + b0;
    float r1 = dx1 * inv * w1 + b1;
    float r2 = dx2 * inv * w2 + b2;
    float r3 = dx3 * inv * w3 + b3;

    if (*flag) {
        float4* wp = (float4*)((float*)outv + (size_t)row * 1024 + c);
        *wp = make_float4(r0, r1, r2, r3);
    } else {
        bf16* wp = (bf16*)outv + (size_t)row * 1024 + c;
        wp[0] = f2bf(r0); wp[1] = f2bf(r1); wp[2] = f2bf(r2); wp[3] = f2bf(r3);
    }
}

// ---------------------------------------------------------------------------
extern "C" void kernel_launch(void* const* d_in, const int* in_sizes, int n_in,
                              void* d_out, int out_size, void* d_ws, size_t ws_size,
                              hipStream_t stream)
{
    const void* x          = d_in[0];
    const void* in_proj_w  = d_in[1];
    const void* conv_w     = d_in[2];
    const void* conv_b     = d_in[3];
    const void* x_proj_w   = d_in[4];
    const void* dt_proj_w  = d_in[5];
    const void* dt_proj_b  = d_in[6];
    const void* A_log      = d_in[7];
    const void* Dvec       = d_in[8];
    const void* out_proj_w = d_in[9];
    const void* ln_w       = d_in[10];
    const void* ln_b       = d_in[11];

    size_t nBig = (size_t)NROWS * D_INNER;
    size_t xdblN = (size_t)NROWS * 96;
    size_t need = (3 * nBig + xdblN + 196608) * 2;   // ~195.5 MB (proven fits)
    if (ws_size < need) {
        hipMemsetAsync(d_out, 0, (size_t)out_size * 2, stream);
        return;
    }

    bf16* bufA = (bf16*)d_ws;       // u -> x_proj_w copy -> delta -> out_proj_w copy
    bf16* bufZ = bufA + nBig;       // z -> y_out
    bf16* bufC = bufZ + nBig;       // x+in_proj_w copies -> u_c / y_gated
    bf16* bufX = bufC + nBig;       // x_dbl
    bf16* bufS = bufX + xdblN;      // flag + small consts

    int*  flag    = (int*)bufS;
    bf16* c_convw = bufS + 16;
    bf16* c_convb = c_convw + 8192;
    bf16* c_dtw   = c_convb + 2048;
    bf16* c_dtb   = c_dtw + 131072;
    bf16* c_Alog  = c_dtb + 2048;
    bf16* c_D     = c_Alog + 32768;
    bf16* c_lnw   = c_D + 2048;
    bf16* c_lnb   = c_lnw + 1024;

    bf16* c_x    = bufC;
    bf16* c_wip  = bufC + (size_t)NROWS * 1024;
    bf16* c_xpw  = bufA;
    bf16* c_opw  = bufA;
    bf16* u      = bufA;
    bf16* delta  = bufA;
    bf16* zbuf   = bufZ;
    bf16* y_out  = bufZ;
    bf16* u_c    = bufC;
    bf16* x_dbl  = bufX;

    // scan P/S scratch in d_out (dead until LayerNorm): 16.8 MB <= 33.5 MB min.
    float* Pbuf = (float*)d_out;
    float* Sbuf = Pbuf + (size_t)BB * NCHUNK * 16 * 2048;

    dim3 blk(256);
    auto cvt = [&](const void* src, bf16* dst, int n) {
        convert_to_bf16<<<dim3((n + 255) / 256), blk, 0, stream>>>(src, dst, n, flag);
    };

    // 0. detect input dtype
    detect_dtype<<<dim3(1), blk, 0, stream>>>(x, flag);

    // small consts
    cvt(conv_w, c_convw, D_INNER * 4);
    cvt(conv_b, c_convb, D_INNER);
    cvt(dt_proj_w, c_dtw, D_INNER * DT_RANK);
    cvt(dt_proj_b, c_dtb, D_INNER);
    cvt(A_log, c_Alog, D_INNER * D_STATE);
    cvt(Dvec, c_D, D_INNER);
    cvt(ln_w, c_lnw, D_MODEL);
    cvt(ln_b, c_lnb, D_MODEL);

    cvt(x, c_x, NROWS * D_MODEL);
    cvt(in_proj_w, c_wip, 2 * D_INNER * D_MODEL);

    // 1. in_proj (MFMA): u and z halves
    gemm_mfma<0><<<dim3(D_INNER / 128, NROWS / 128), blk, 0, stream>>>(
        c_x, D_MODEL, c_wip, D_MODEL, D_MODEL, nullptr, u, D_INNER, NROWS, D_INNER);
    gemm_mfma<0><<<dim3(D_INNER / 128, NROWS / 128), blk, 0, stream>>>(
        c_x, D_MODEL, c_wip + (size_t)D_INNER * D_MODEL, D_MODEL, D_MODEL, nullptr,
        zbuf, D_INNER, NROWS, D_INNER);

    // 2. conv + SiLU -> u_c (bufC's copies die here)
    conv_silu<<<dim3((NROWS * D_INNER) / 256), blk, 0, stream>>>(u, u_c, c_convw, c_convb);

    // 3. x_proj (N=96, one N-tile)
    cvt(x_proj_w, c_xpw, 96 * D_INNER);
    gemm_mfma<0><<<dim3(1, NROWS / 128), blk, 0, stream>>>(
        u_c, D_INNER, c_xpw, D_INNER, D_INNER, nullptr, x_dbl, 96, NROWS, 96);

    // 4. dt_proj + softplus -> delta (K=64, A = x_dbl first 64 cols, lda=96)
    gemm_mfma<1><<<dim3(D_INNER / 128, NROWS / 128), blk, 0, stream>>>(
        x_dbl, 96, c_dtw, DT_RANK, DT_RANK, c_dtb, delta, D_INNER, NROWS, D_INNER);

    // 5. chunked selective scan (3 phases), gate fused; in-place into u_c
    scan_p1<<<dim3(BB * NCHUNK * 8), blk, 0, stream>>>(delta, u_c, x_dbl, c_Alog, Pbuf, Sbuf);
    scan_p2<<<dim3(BB * 16 * 2048 / 256), blk, 0, stream>>>(Pbuf, Sbuf);
    scan_p3<<<dim3(BB * NCHUNK * 8), blk, 0, stream>>>(
        delta, u_c, x_dbl, zbuf, c_Alog, c_D, Pbuf, u_c);

    // 6. out_proj -> y_out in bufZ
    cvt(out_proj_w, c_opw, D_MODEL * D_INNER);
    gemm_mfma<0><<<dim3(D_MODEL / 128, NROWS / 128), blk, 0, stream>>>(
        u_c, D_INNER, c_opw, D_INNER, D_INNER, nullptr, y_out, D_MODEL, NROWS, D_MODEL);

    // 7. LayerNorm -> d_out
    out_ln<<<dim3(NROWS), blk, 0, stream>>>(y_out, c_lnw, c_lnb, d_out, flag);
}

// Round 7
// 995.443 us; speedup vs baseline: 4.4834x; 1.1004x over previous
//
#include <hip/hip_runtime.h>
#include <hip/hip_bf16.h>
#include <math.h>

#define D_MODEL 1024
#define D_INNER 2048
#define D_STATE 16
#define DT_RANK 64
#define BB 4
#define LL 4096
#define NROWS (BB * LL)   // 16384
#define NCHUNK 16
#define TCHUNK 256        // NCHUNK * TCHUNK == LL

typedef __hip_bfloat16 bf16;
typedef __attribute__((ext_vector_type(8))) short short8;   // MFMA A/B frag (8 bf16)
typedef __attribute__((ext_vector_type(4))) float floatx4;  // MFMA C/D frag

__device__ __forceinline__ float silu_f(float x) { return x / (1.f + __expf(-x)); }
__device__ __forceinline__ float softplus_f(float x) { return x > 20.f ? x : log1pf(__expf(x)); }
__device__ __forceinline__ float bf2f(bf16 v) { return __bfloat162float(v); }
__device__ __forceinline__ bf16 f2bf(float v) { return __float2bfloat16(v); }

// async 16B global -> LDS copy (gfx950 global_load_lds_dwordx4).
// HW semantics: LDS dest = wave-uniform base + lane*16 [m97/m104].
__device__ __forceinline__ void gl2lds16(const bf16* g, short* lds) {
    __builtin_amdgcn_global_load_lds(
        (const __attribute__((address_space(1))) void*)g,
        (__attribute__((address_space(3))) void*)lds, 16, 0, 0);
}

// decode 8 consecutive bf16 (16-byte aligned) to fp32
__device__ __forceinline__ void load8_bf16(const bf16* p, float* f) {
    uint4 raw = *(const uint4*)p;
    unsigned int w0 = raw.x, w1 = raw.y, w2 = raw.z, w3 = raw.w;
    f[0] = __uint_as_float((w0 & 0xffffu) << 16);
    f[1] = __uint_as_float(w0 & 0xffff0000u);
    f[2] = __uint_as_float((w1 & 0xffffu) << 16);
    f[3] = __uint_as_float(w1 & 0xffff0000u);
    f[4] = __uint_as_float((w2 & 0xffffu) << 16);
    f[5] = __uint_as_float(w2 & 0xffff0000u);
    f[6] = __uint_as_float((w3 & 0xffffu) << 16);
    f[7] = __uint_as_float(w3 & 0xffff0000u);
}

// ---------------------------------------------------------------------------
// Input dtype detection (1 = fp32 inputs, 0 = bf16 inputs).
// ---------------------------------------------------------------------------
__global__ void detect_dtype(const void* xsrc, int* flag) {
    const unsigned short* p = (const unsigned short*)xsrc;
    int tid = threadIdx.x;
    int bad = 0;
    for (int i = tid; i < 2048; i += 256) {
        float v = __uint_as_float(((unsigned int)p[i]) << 16);
        if (!isfinite(v) || fabsf(v) > 1e6f) bad = 1;
    }
    __shared__ int sbad;
    if (tid == 0) sbad = 0;
    __syncthreads();
    if (bad) atomicOr(&sbad, 1);
    __syncthreads();
    if (tid == 0) *flag = sbad;
}

__global__ __launch_bounds__(256) void convert_to_bf16(
    const void* __restrict__ src, bf16* __restrict__ dst, int n,
    const int* __restrict__ flag)
{
    int i = blockIdx.x * 256 + threadIdx.x;
    if (i >= n) return;
    if (*flag)
        dst[i] = f2bf(((const float*)src)[i]);
    else
        dst[i] = ((const bf16*)src)[i];
}

// batch of small conversions in a single dispatch (saves ~7 launches)
struct CvtBatch {
    const void* src[8];
    bf16* dst[8];
    int n[8];
    int blockStart[9];   // prefix of ceil(n/256)
    int count;
};
__global__ __launch_bounds__(256) void convert_batch(CvtBatch b, const int* __restrict__ flag) {
    int bi = blockIdx.x;
    int seg = 0;
    while (seg + 1 < b.count && bi >= b.blockStart[seg + 1]) seg++;
    int i = (bi - b.blockStart[seg]) * 256 + threadIdx.x;
    if (i >= b.n[seg]) return;
    if (*flag)
        b.dst[seg][i] = f2bf(((const float*)b.src[seg])[i]);
    else
        b.dst[seg][i] = ((const bf16*)b.src[seg])[i];
}

// ---------------------------------------------------------------------------
// Async-staged MFMA bf16 GEMM: C[M,N] = A[M,K] @ W[N,K]^T, fp32 accumulate.
// 128x128 tile, BK=32, 256 threads = 4 waves (2x2), wave = 4x4 of 16x16x32.
// Staging via global_load_lds 16B chunks: chunk c (row=c>>2, seg=c&3) lands
// at shorts [c*8] == row*32+seg*8 — lane-contiguous [m97 pattern].
// W rows beyond N are clamped (duplicate data); their C cols are not stored.
// EPI: 0 plain, 1 softplus(x+bias[n]), 2 split store at Nsplit (C / C2).
// ---------------------------------------------------------------------------
template <int EPI>
__global__ __launch_bounds__(256) void gemm_async(
    const bf16* __restrict__ A, int lda,
    const bf16* __restrict__ W, int ldw, int K,
    const bf16* __restrict__ bias,
    bf16* __restrict__ C, bf16* __restrict__ C2, int ldc,
    int N, int Nsplit)
{
    __shared__ short As[128 * 32];   // [m][k], 8 KB
    __shared__ short Bs[128 * 32];   // [n][k], 8 KB

    const int tid = threadIdx.x;
    const int m0 = blockIdx.y * 128;
    const int n0 = blockIdx.x * 128;
    const int wid = tid >> 6;
    const int lane = tid & 63;
    const int wm = wid & 1;
    const int wn = wid >> 1;
    const int lm = lane & 15;
    const int quad = lane >> 4;

    floatx4 acc[4][4];
#pragma unroll
    for (int i = 0; i < 4; i++)
#pragma unroll
        for (int j = 0; j < 4; j++) acc[i][j] = (floatx4){0.f, 0.f, 0.f, 0.f};

    for (int k0 = 0; k0 < K; k0 += 32) {
        // A tile: 512 chunks, 8 issues (2 per wave)
#pragma unroll
        for (int j = 0; j < 2; j++) {
            int cbase = (wid * 2 + j) * 64;       // wave-uniform
            int c = cbase + lane;
            int row = c >> 2, seg = c & 3;
            gl2lds16(A + (size_t)(m0 + row) * lda + k0 + seg * 8, &As[cbase * 8]);
        }
        // W tile (clamp OOB rows; their outputs are masked at store)
#pragma unroll
        for (int j = 0; j < 2; j++) {
            int cbase = (wid * 2 + j) * 64;
            int c = cbase + lane;
            int row = c >> 2, seg = c & 3;
            int wrow = n0 + row; if (wrow >= N) wrow = N - 1;
            gl2lds16(W + (size_t)wrow * ldw + k0 + seg * 8, &Bs[cbase * 8]);
        }
        __syncthreads();   // drains vmcnt: staging visible

        short8 af[4], bfr[4];
#pragma unroll
        for (int mt = 0; mt < 4; mt++)
            af[mt] = *(const short8*)&As[(wm * 64 + mt * 16 + lm) * 32 + quad * 8];
#pragma unroll
        for (int nt = 0; nt < 4; nt++)
            bfr[nt] = *(const short8*)&Bs[(wn * 64 + nt * 16 + lm) * 32 + quad * 8];
        __syncthreads();   // frags in regs; LDS free for next-iter staging

#pragma unroll
        for (int mt = 0; mt < 4; mt++)
#pragma unroll
            for (int nt = 0; nt < 4; nt++)
                acc[mt][nt] = __builtin_amdgcn_mfma_f32_16x16x32_bf16(
                    af[mt], bfr[nt], acc[mt][nt], 0, 0, 0);
    }

    // epilogue: col = lane&15, row = quad*4 + r  [m89/m91]
#pragma unroll
    for (int mt = 0; mt < 4; mt++) {
#pragma unroll
        for (int nt = 0; nt < 4; nt++) {
            int col = n0 + wn * 64 + nt * 16 + lm;
            if (col >= N) continue;
            int rbase = m0 + wm * 64 + mt * 16 + quad * 4;
#pragma unroll
            for (int r = 0; r < 4; r++) {
                float v = acc[mt][nt][r];
                if (EPI == 1) v = softplus_f(v + bf2f(bias[col]));
                if (EPI == 2) {
                    if (col < Nsplit)
                        C[(size_t)(rbase + r) * ldc + col] = f2bf(v);
                    else
                        C2[(size_t)(rbase + r) * ldc + (col - Nsplit)] = f2bf(v);
                } else {
                    C[(size_t)(rbase + r) * ldc + col] = f2bf(v);
                }
            }
        }
    }
}

// ---------------------------------------------------------------------------
// Causal depthwise conv1d (width 4) + bias + SiLU. bf16 in/out, fp32 math.
// ---------------------------------------------------------------------------
__global__ __launch_bounds__(256) void conv_silu(
    const bf16* __restrict__ u,
    bf16* __restrict__ u_c,
    const bf16* __restrict__ w,
    const bf16* __restrict__ bias)
{
    int gid = blockIdx.x * 256 + threadIdx.x;
    if (gid >= NROWS * D_INNER) return;
    int d = gid & (D_INNER - 1);
    int row = gid >> 11;
    int l = row & (LL - 1);
    float acc = bf2f(bias[d]);
#pragma unroll
    for (int t = 0; t < 4; t++) {
        int ls = l - 3 + t;
        if (ls >= 0)
            acc = fmaf(bf2f(w[d * 4 + t]), bf2f(u[(size_t)(row - 3 + t) * D_INNER + d]), acc);
    }
    u_c[(size_t)row * D_INNER + d] = f2bf(silu_f(acc));
}

// ---------------------------------------------------------------------------
// Chunked selective scan (3 phases). See round-5 notes.
// ---------------------------------------------------------------------------
__global__ __launch_bounds__(256) void scan_p1(
    const bf16* __restrict__ delta,
    const bf16* __restrict__ uc,
    const bf16* __restrict__ x_dbl,
    const bf16* __restrict__ A_log,
    float* __restrict__ Pbuf, float* __restrict__ Sbuf)
{
    __shared__ float Bsh[TCHUNK * 16];
    const int tid = threadIdx.x;
    const int bx = blockIdx.x;
    const int b = bx >> 7;
    const int c = (bx >> 3) & 15;
    const int dt = bx & 7;
    const int d = dt * 256 + tid;
    const int rowb = b * LL + c * TCHUNK;

    {
        float f[16];
        const bf16* p = x_dbl + (size_t)(rowb + tid) * 96 + DT_RANK;
        load8_bf16(p, f);
        load8_bf16(p + 8, f + 8);
#pragma unroll
        for (int n = 0; n < 16; n++) Bsh[tid * 16 + n] = f[n];
    }

    float Ac[16];
    {
        float f[16];
        load8_bf16(A_log + (size_t)d * 16, f);
        load8_bf16(A_log + (size_t)d * 16 + 8, f + 8);
#pragma unroll
        for (int n = 0; n < 16; n++) Ac[n] = -__expf(f[n]);
    }
    __syncthreads();

    float h[16], Pp[16];
#pragma unroll
    for (int n = 0; n < 16; n++) { h[n] = 0.f; Pp[n] = 1.f; }

    size_t g = (size_t)rowb * 2048 + d;
    float dl = bf2f(delta[g]);
    float uv = bf2f(uc[g]);
    for (int t = 0; t < TCHUNK; t++) {
        float dl_n = 0.f, uv_n = 0.f;
        if (t + 1 < TCHUNK) {
            g += 2048;
            dl_n = bf2f(delta[g]);
            uv_n = bf2f(uc[g]);
        }
        float dlu = dl * uv;
#pragma unroll
        for (int n = 0; n < 16; n++) {
            float dA = __expf(dl * Ac[n]);
            h[n] = fmaf(dA, h[n], dlu * Bsh[t * 16 + n]);
            Pp[n] *= dA;
        }
        dl = dl_n; uv = uv_n;
    }

    size_t base = (((size_t)b * NCHUNK + c) * 16) * 2048 + d;
#pragma unroll
    for (int n = 0; n < 16; n++) {
        Pbuf[base + (size_t)n * 2048] = Pp[n];
        Sbuf[base + (size_t)n * 2048] = h[n];
    }
}

__global__ __launch_bounds__(256) void scan_p2(
    float* __restrict__ Pbuf, const float* __restrict__ Sbuf)
{
    int gid = blockIdx.x * 256 + threadIdx.x;
    int b = gid >> 15;
    int n = (gid >> 11) & 15;
    int d = gid & 2047;
    float hinit = 0.f;
    for (int c = 0; c < NCHUNK; c++) {
        size_t idx = (((size_t)b * NCHUNK + c) * 16 + n) * 2048 + d;
        float p = Pbuf[idx];
        float s = Sbuf[idx];
        Pbuf[idx] = hinit;
        hinit = fmaf(p, hinit, s);
    }
}

__global__ __launch_bounds__(256) void scan_p3(
    const bf16* __restrict__ delta,
    const bf16* uc,
    const bf16* __restrict__ x_dbl,
    const bf16* __restrict__ z,
    const bf16* __restrict__ A_log,
    const bf16* __restrict__ Dvec,
    const float* __restrict__ Hinit,
    bf16* yg)
{
    __shared__ float Bsh[TCHUNK * 16];
    __shared__ float Csh[TCHUNK * 16];
    const int tid = threadIdx.x;
    const int bx = blockIdx.x;
    const int b = bx >> 7;
    const int c = (bx >> 3) & 15;
    const int dt = bx & 7;
    const int d = dt * 256 + tid;
    const int rowb = b * LL + c * TCHUNK;

    {
        float f[16];
        const bf16* p = x_dbl + (size_t)(rowb + tid) * 96 + DT_RANK;
        load8_bf16(p, f);
        load8_bf16(p + 8, f + 8);
#pragma unroll
        for (int n = 0; n < 16; n++) Bsh[tid * 16 + n] = f[n];
        load8_bf16(p + 16, f);
        load8_bf16(p + 24, f + 8);
#pragma unroll
        for (int n = 0; n < 16; n++) Csh[tid * 16 + n] = f[n];
    }

    float Ac[16];
    {
        float f[16];
        load8_bf16(A_log + (size_t)d * 16, f);
        load8_bf16(A_log + (size_t)d * 16 + 8, f + 8);
#pragma unroll
        for (int n = 0; n < 16; n++) Ac[n] = -__expf(f[n]);
    }
    const float Dv = bf2f(Dvec[d]);
    __syncthreads();

    float h[16];
    size_t base = (((size_t)b * NCHUNK + c) * 16) * 2048 + d;
#pragma unroll
    for (int n = 0; n < 16; n++) h[n] = Hinit[base + (size_t)n * 2048];

    size_t g = (size_t)rowb * 2048 + d;
    float dl = bf2f(delta[g]);
    float uv = bf2f(uc[g]);
    float zv = bf2f(z[g]);
    size_t gw = g;
    for (int t = 0; t < TCHUNK; t++) {
        float dl_n = 0.f, uv_n = 0.f, zv_n = 0.f;
        if (t + 1 < TCHUNK) {
            g += 2048;
            dl_n = bf2f(delta[g]);
            uv_n = bf2f(uc[g]);
            zv_n = bf2f(z[g]);
        }
        float dlu = dl * uv;
        float y = 0.f;
#pragma unroll
        for (int n = 0; n < 16; n++) {
            float dA = __expf(dl * Ac[n]);
            h[n] = fmaf(dA, h[n], dlu * Bsh[t * 16 + n]);
            y = fmaf(h[n], Csh[t * 16 + n], y);
        }
        y = fmaf(uv, Dv, y);
        yg[gw] = f2bf(y * silu_f(zv));
        gw += 2048;
        dl = dl_n; uv = uv_n; zv = zv_n;
    }
}

// ---------------------------------------------------------------------------
// LayerNorm over last dim (1024). Output dtype per flag (1=fp32, 0=bf16).
// ---------------------------------------------------------------------------
__global__ __launch_bounds__(256) void out_ln(
    const bf16* __restrict__ o,
    const bf16* __restrict__ lw,
    const bf16* __restrict__ lb,
    void* __restrict__ outv,
    const int* __restrict__ flag)
{
    __shared__ float sm[4];
    const int row = blockIdx.x;
    const int tid = threadIdx.x;
    const int lane = tid & 63;
    const int wid = tid >> 6;
    const int c = tid * 4;

    const bf16* rp = o + (size_t)row * 1024 + c;
    float v0 = bf2f(rp[0]), v1 = bf2f(rp[1]), v2 = bf2f(rp[2]), v3 = bf2f(rp[3]);

    float s = v0 + v1 + v2 + v3;
#pragma unroll
    for (int off = 1; off < 64; off <<= 1) s += __shfl_xor(s, off, 64);
    if (lane == 0) sm[wid] = s;
    __syncthreads();
    float mu = (sm[0] + sm[1] + sm[2] + sm[3]) * (1.f / 1024.f);
    __syncthreads();

    float dx0 = v0 - mu, dx1 = v1 - mu, dx2 = v2 - mu, dx3 = v3 - mu;
    float q = dx0 * dx0 + dx1 * dx1 + dx2 * dx2 + dx3 * dx3;
#pragma unroll
    for (int off = 1; off < 64; off <<= 1) q += __shfl_xor(q, off, 64);
    if (lane == 0) sm[wid] = q;
    __syncthreads();
    float var = (sm[0] + sm[1] + sm[2] + sm[3]) * (1.f / 1024.f);
    float inv = rsqrtf(var + 1e-5f);

    float w0 = bf2f(lw[c]), w1 = bf2f(lw[c + 1]), w2 = bf2f(lw[c + 2]), w3 = bf2f(lw[c + 3]);
    float b0 = bf2f(lb[c]), b1 = bf2f(lb[c + 1]), b2 = bf2f(lb[c + 2]), b3 = bf2f(lb[c + 3]);
    float r0 = dx0 * inv * w0 + b0;
    float r1 = dx1 * inv * w1 + b1;
    float r2 = dx2 * inv * w2 + b2;
    float r3 = dx3 * inv * w3 + b3;

    if (*flag) {
        float4* wp = (float4*)((float*)outv + (size_t)row * 1024 + c);
        *wp = make_float4(r0, r1, r2, r3);
    } else {
        bf16* wp = (bf16*)outv + (size_t)row * 1024 + c;
        wp[0] = f2bf(r0); wp[1] = f2bf(r1); wp[2] = f2bf(r2); wp[3] = f2bf(r3);
    }
}

// ---------------------------------------------------------------------------
extern "C" void kernel_launch(void* const* d_in, const int* in_sizes, int n_in,
                              void* d_out, int out_size, void* d_ws, size_t ws_size,
                              hipStream_t stream)
{
    const void* x          = d_in[0];
    const void* in_proj_w  = d_in[1];
    const void* conv_w     = d_in[2];
    const void* conv_b     = d_in[3];
    const void* x_proj_w   = d_in[4];
    const void* dt_proj_w  = d_in[5];
    const void* dt_proj_b  = d_in[6];
    const void* A_log      = d_in[7];
    const void* Dvec       = d_in[8];
    const void* out_proj_w = d_in[9];
    const void* ln_w       = d_in[10];
    const void* ln_b       = d_in[11];

    size_t nBig = (size_t)NROWS * D_INNER;
    size_t xdblN = (size_t)NROWS * 96;
    size_t need = (3 * nBig + xdblN + 196608) * 2;   // ~195.5 MB (proven fits)
    if (ws_size < need) {
        hipMemsetAsync(d_out, 0, (size_t)out_size * 2, stream);
        return;
    }

    bf16* bufA = (bf16*)d_ws;       // u -> x_proj_w copy -> delta -> out_proj_w copy
    bf16* bufZ = bufA + nBig;       // z -> y_out
    bf16* bufC = bufZ + nBig;       // x+in_proj_w copies -> u_c / y_gated
    bf16* bufX = bufC + nBig;       // x_dbl
    bf16* bufS = bufX + xdblN;      // flag + small consts

    int*  flag    = (int*)bufS;
    bf16* c_convw = bufS + 16;
    bf16* c_convb = c_convw + 8192;
    bf16* c_dtw   = c_convb + 2048;
    bf16* c_dtb   = c_dtw + 131072;
    bf16* c_Alog  = c_dtb + 2048;
    bf16* c_D     = c_Alog + 32768;
    bf16* c_lnw   = c_D + 2048;
    bf16* c_lnb   = c_lnw + 1024;

    bf16* c_x    = bufC;
    bf16* c_wip  = bufC + (size_t)NROWS * 1024;
    bf16* c_xpw  = bufA;
    bf16* c_opw  = bufA;
    bf16* u      = bufA;
    bf16* delta  = bufA;
    bf16* zbuf   = bufZ;
    bf16* y_out  = bufZ;
    bf16* u_c    = bufC;
    bf16* x_dbl  = bufX;

    // scan P/S scratch in d_out (dead until LayerNorm): 16.8 MB <= 33.5 MB min.
    float* Pbuf = (float*)d_out;
    float* Sbuf = Pbuf + (size_t)BB * NCHUNK * 16 * 2048;

    dim3 blk(256);
    auto cvt = [&](const void* src, bf16* dst, int n) {
        convert_to_bf16<<<dim3((n + 255) / 256), blk, 0, stream>>>(src, dst, n, flag);
    };

    // 0. detect input dtype
    detect_dtype<<<dim3(1), blk, 0, stream>>>(x, flag);

    // small consts: one batched dispatch
    {
        CvtBatch b{};
        const void* srcs[8] = {conv_w, conv_b, dt_proj_w, dt_proj_b, A_log, Dvec, ln_w, ln_b};
        bf16* dsts[8] = {c_convw, c_convb, c_dtw, c_dtb, c_Alog, c_D, c_lnw, c_lnb};
        int ns[8] = {D_INNER * 4, D_INNER, D_INNER * DT_RANK, D_INNER,
                     D_INNER * D_STATE, D_INNER, D_MODEL, D_MODEL};
        int acc = 0;
        for (int i = 0; i < 8; i++) {
            b.src[i] = srcs[i]; b.dst[i] = dsts[i]; b.n[i] = ns[i];
            b.blockStart[i] = acc; acc += (ns[i] + 255) / 256;
        }
        b.blockStart[8] = acc; b.count = 8;
        convert_batch<<<dim3(acc), blk, 0, stream>>>(b, flag);
    }

    cvt(x, c_x, NROWS * D_MODEL);
    cvt(in_proj_w, c_wip, 2 * D_INNER * D_MODEL);

    // 1. in_proj: one dispatch, N=4096, split store u | z
    gemm_async<2><<<dim3(2 * D_INNER / 128, NROWS / 128), blk, 0, stream>>>(
        c_x, D_MODEL, c_wip, D_MODEL, D_MODEL, nullptr,
        u, zbuf, D_INNER, 2 * D_INNER, D_INNER);

    // 2. conv + SiLU -> u_c (bufC copies die here)
    conv_silu<<<dim3((NROWS * D_INNER) / 256), blk, 0, stream>>>(u, u_c, c_convw, c_convb);

    // 3. x_proj (N=96)
    cvt(x_proj_w, c_xpw, 96 * D_INNER);
    gemm_async<0><<<dim3(1, NROWS / 128), blk, 0, stream>>>(
        u_c, D_INNER, c_xpw, D_INNER, D_INNER, nullptr,
        x_dbl, nullptr, 96, 96, 0);

    // 4. dt_proj + softplus -> delta (K=64, A = x_dbl cols 0..63, lda=96)
    gemm_async<1><<<dim3(D_INNER / 128, NROWS / 128), blk, 0, stream>>>(
        x_dbl, 96, c_dtw, DT_RANK, DT_RANK, c_dtb,
        delta, nullptr, D_INNER, D_INNER, 0);

    // 5. chunked selective scan (3 phases), gate fused; in-place into u_c
    scan_p1<<<dim3(BB * NCHUNK * 8), blk, 0, stream>>>(delta, u_c, x_dbl, c_Alog, Pbuf, Sbuf);
    scan_p2<<<dim3(BB * 16 * 2048 / 256), blk, 0, stream>>>(Pbuf, Sbuf);
    scan_p3<<<dim3(BB * NCHUNK * 8), blk, 0, stream>>>(
        delta, u_c, x_dbl, zbuf, c_Alog, c_D, Pbuf, u_c);

    // 6. out_proj -> y_out in bufZ
    cvt(out_proj_w, c_opw, D_MODEL * D_INNER);
    gemm_async<0><<<dim3(D_MODEL / 128, NROWS / 128), blk, 0, stream>>>(
        u_c, D_INNER, c_opw, D_INNER, D_INNER, nullptr,
        y_out, nullptr, D_MODEL, D_MODEL, 0);

    // 7. LayerNorm -> d_out
    out_ln<<<dim3(NROWS), blk, 0, stream>>>(y_out, c_lnw, c_lnb, d_out, flag);
}